// Round 9
// baseline (117.748 us; speedup 1.0000x reference)
//
#include <hip/hip_runtime.h>
#include <math.h>

#define B 8
#define T 128
#define NKEY 127   // t-1
#define NPAD 128   // padded key count (score row 127 forced to prob 0)
#define KDIM 64    // Q_DIM == KV_DIM
#define NH 4       // heads
#define CH 256     // NH*KDIM output channels

typedef short short8 __attribute__((ext_vector_type(8)));   // 8 bf16 (4 VGPRs)
typedef float floatx4 __attribute__((ext_vector_type(4)));  // MFMA C/D

// tanh(x) = 1 - 2/(e^{2x}+1). Saturates correctly at +/-inf, no clamp needed.
__device__ __forceinline__ float fast_tanh(float x) {
    float e = __expf(2.f * x);
    float r = __builtin_amdgcn_rcpf(e + 1.f);
    return fmaf(-2.f, r, 1.f);
}

// Round-to-nearest-even bf16 x8 (hi-only path for both A and B fragments).
__device__ __forceinline__ void rne8(const float4& a, const float4& b, short8& hi) {
    float x[8] = {a.x, a.y, a.z, a.w, b.x, b.y, b.z, b.w};
    #pragma unroll
    for (int i = 0; i < 8; ++i) {
        unsigned u = __float_as_uint(x[i]);
        u += 0x7FFFu + ((u >> 16) & 1u);
        hi[i] = (short)(u >> 16);
    }
}

// One workgroup per (b,t): 4 waves; wave h == head h.
// R9 = R8 skeleton with three work-halvings (R8 was latency-bound, all pipes
// <35%, ~185 VMEM instrs/wave):
//  (1) B-fragments hi-only RNE bf16: MFMA 16->8 per nt, conversion VALU and
//      frag LDS traffic halved, bl_lds dropped (LDS 36.8 -> 20.5 KB).
//      Error budget: +~3e-4 on scores; total ~1e-3 < 3.5e-3 threshold.
//  (2) Phase B float4 quad-row mapping: 32 coalesced dwordx4 loads instead of
//      128 scalar dwords per wave; cross-quad shuffle reduce (R6 pattern).
//  (3) __launch_bounds__(256,2) kept: arg2=4 provably caps VGPR=64 -> spill.
__global__ __launch_bounds__(256, 2)
void attn_kernel(const float* __restrict__ q_x,   // (B,T,64)
                 const float* __restrict__ kv_x,  // (B,T,127,64)
                 const float* __restrict__ Wk,    // (256,64)
                 const float* __restrict__ Wq,    // (256,64)
                 const float* __restrict__ Wv,    // (256,64)
                 const float* __restrict__ bias,  // (64,)
                 const float* __restrict__ Ws,    // (1,64)
                 const float* __restrict__ bs,    // (1,) -- cancels in softmax
                 float* __restrict__ out)         // (B,T,256)
{
    __shared__ __align__(16) short bh_lds[16][64][8];    // 16 KB: B-frag hi [chunk][lane][8]
    __shared__ float qb_lds[CH];                         // 1 KB: query+bias per channel
    __shared__ float p_lds[NH][NPAD];                    // 2 KB: scores then probs
    __shared__ __align__(16) float wkv_lds[NH][KDIM];    // 1 KB -> total 20992 B

    const int bt   = blockIdx.x;
    const int tid  = threadIdx.x;
    const int h    = tid >> 6;    // wave index == head index
    const int lane = tid & 63;
    const int col  = lane & 15;   // MFMA n/m lane index
    const int quad = lane >> 4;   // MFMA k-group / row-group

    const float* __restrict__ kvg = kv_x + (size_t)bt * NKEY * KDIM;

    // ---- convert kv (global) -> fragment-ordered bf16-hi LDS ----
    // chunk = nt*2+ks; write addr = chunk*1024 + lane*16: lane-linear, 0 conflicts.
    // Fragment content: kv[nt*16 + (lane&15)][ks*32 + (lane>>4)*8 + j]
    #pragma unroll
    for (int w = 0; w < 4; ++w) {
        const int chunk = w * 4 + h;          // each wave does 4 chunks
        const int nt = chunk >> 1, ks = chunk & 1;
        const int n  = nt * 16 + (lane & 15);
        const int k0 = ks * 32 + (lane >> 4) * 8;
        float4 a = make_float4(0.f, 0.f, 0.f, 0.f);
        float4 b = make_float4(0.f, 0.f, 0.f, 0.f);
        if (n < NKEY) {
            const float* p = kvg + (size_t)n * KDIM + k0;
            a = *(const float4*)p;
            b = *(const float4*)(p + 4);
        }
        short8 hi;
        rne8(a, b, hi);
        *(short8*)&bh_lds[chunk][lane][0] = hi;
    }

    // ---- query_j + bias -> qb_lds[channel] ----
    {
        const float4* Wq4 = (const float4*)(Wq + (size_t)tid * KDIM);
        const float4* q4g = (const float4*)(q_x + (size_t)bt * KDIM);
        float4 qa = {0.f, 0.f, 0.f, 0.f};
        #pragma unroll
        for (int i = 0; i < 16; ++i) {
            float4 w = Wq4[i];
            float4 q4 = q4g[i];
            qa.x = fmaf(q4.x, w.x, qa.x);
            qa.y = fmaf(q4.y, w.y, qa.y);
            qa.z = fmaf(q4.z, w.z, qa.z);
            qa.w = fmaf(q4.w, w.w, qa.w);
        }
        qb_lds[tid] = (qa.x + qa.y) + (qa.z + qa.w) + bias[tid & 63];
    }

    // ---- A-fragments: Wk rows of this head, RNE bf16 hi only ----
    // A layout: lane holds Wk[h*64 + jt*16 + col][ks*32 + quad*8 + j]
    short8 ahi[4][2];
    #pragma unroll
    for (int jt = 0; jt < 4; ++jt)
        #pragma unroll
        for (int ks = 0; ks < 2; ++ks) {
            const float* wrow = Wk + (size_t)(h * 64 + jt * 16 + col) * KDIM
                                   + ks * 32 + quad * 8;
            float4 a = *(const float4*)wrow;
            float4 b = *(const float4*)(wrow + 4);
            rne8(a, b, ahi[jt][ks]);
        }

    __syncthreads();   // barrier: frags + qb ready

    // ---- per-lane qb / ws for epilogue: j = jt*16 + quad*4 + r ----
    float qbv[4][4], wsv[4][4];
    #pragma unroll
    for (int jt = 0; jt < 4; ++jt)
        #pragma unroll
        for (int r = 0; r < 4; ++r) {
            int j = jt * 16 + quad * 4 + r;
            qbv[jt][r] = qb_lds[h * 64 + j];
            wsv[jt][r] = Ws[j];
        }

    // ---- scores: 8 n-tiles of 16 keys; Ahi·Bhi MFMA ----
    #pragma unroll
    for (int nt = 0; nt < 8; ++nt) {
        short8 bhi0 = *(const short8*)&bh_lds[nt * 2 + 0][lane][0];
        short8 bhi1 = *(const short8*)&bh_lds[nt * 2 + 1][lane][0];

        floatx4 acc[4];
        #pragma unroll
        for (int jt = 0; jt < 4; ++jt) {
            floatx4 c = {0.f, 0.f, 0.f, 0.f};
            c = __builtin_amdgcn_mfma_f32_16x16x32_bf16(ahi[jt][0], bhi0, c, 0, 0, 0);
            c = __builtin_amdgcn_mfma_f32_16x16x32_bf16(ahi[jt][1], bhi1, c, 0, 0, 0);
            acc[jt] = c;
        }

        // epilogue: score[n] = sum_j tanh(key + qb[j]) * ws[j]
        // D layout: col = lane&15 = n in tile, row = quad*4 + r = j in jt
        float partial = 0.f;
        #pragma unroll
        for (int jt = 0; jt < 4; ++jt)
            #pragma unroll
            for (int r = 0; r < 4; ++r)
                partial = fmaf(fast_tanh(acc[jt][r] + qbv[jt][r]), wsv[jt][r], partial);
        partial += __shfl_xor(partial, 16, 64);   // reduce across quads (same col)
        partial += __shfl_xor(partial, 32, 64);
        if (lane < 16) p_lds[h][nt * 16 + lane] = partial;
    }
    // no barrier: wave h is sole writer+reader of p_lds[h][*] (DS in-order)

    // ---- softmax over the 127 real keys (2 scores per lane) ----
    float invl;
    {
        float s_a = p_lds[h][lane];
        float s_b = p_lds[h][64 + lane];
        if (lane == 63) s_b = -1e30f;          // mask pad row 127
        float mx = fmaxf(s_a, s_b);
        #pragma unroll
        for (int off = 32; off > 0; off >>= 1)
            mx = fmaxf(mx, __shfl_xor(mx, off, 64));
        float pa = __expf(s_a - mx);
        float pb = __expf(s_b - mx);           // lane 63 -> 0
        float ls = pa + pb;
        #pragma unroll
        for (int off = 32; off > 0; off >>= 1)
            ls += __shfl_xor(ls, off, 64);
        invl = 1.f / ls;
        p_lds[h][lane]      = pa;              // unnormalized probs
        p_lds[h][64 + lane] = pb;              // p_lds[h][127] = 0 masks pad
    }

    // ---- Phase B: wkv[h][:] = (sum_n p[n] * kv[n][:]) / l, float4 loads ----
    // lane (col,quad) accumulates k = 4col..4col+3 over rows n = 4i+quad.
    // Each instr: 64 lanes read 4 consecutive full rows -> perfectly coalesced,
    // L2-hot (same lines read during conversion). 32 loads vs R8's 128.
    {
        float4 a4 = make_float4(0.f, 0.f, 0.f, 0.f);
        #pragma unroll
        for (int i = 0; i < 31; ++i) {
            const int n = 4 * i + quad;
            float4 v = *(const float4*)&kvg[(size_t)n * KDIM + 4 * col];
            const float pn = p_lds[h][n];      // uniform broadcast
            a4.x = fmaf(pn, v.x, a4.x);
            a4.y = fmaf(pn, v.y, a4.y);
            a4.z = fmaf(pn, v.z, a4.z);
            a4.w = fmaf(pn, v.w, a4.w);
        }
        {   // last group: rows 124..127; row 127 doesn't exist -> read row 0, p=0
            const int n = 124 + quad;
            const int n_eff = (n < NKEY) ? n : 0;
            float4 v = *(const float4*)&kvg[(size_t)n_eff * KDIM + 4 * col];
            const float pn = p_lds[h][n];      // p_lds[h][127] == 0
            a4.x = fmaf(pn, v.x, a4.x);
            a4.y = fmaf(pn, v.y, a4.y);
            a4.z = fmaf(pn, v.z, a4.z);
            a4.w = fmaf(pn, v.w, a4.w);
        }
        a4.x += __shfl_xor(a4.x, 16, 64);  a4.y += __shfl_xor(a4.y, 16, 64);
        a4.z += __shfl_xor(a4.z, 16, 64);  a4.w += __shfl_xor(a4.w, 16, 64);
        a4.x += __shfl_xor(a4.x, 32, 64);  a4.y += __shfl_xor(a4.y, 32, 64);
        a4.z += __shfl_xor(a4.z, 32, 64);  a4.w += __shfl_xor(a4.w, 32, 64);
        if (lane < 16) {
            float4 r = make_float4(a4.x * invl, a4.y * invl, a4.z * invl, a4.w * invl);
            *(float4*)&wkv_lds[h][4 * col] = r;
        }
    }
    // no barrier: wkv_lds[h] written and read only by wave h (DS in-order)

    // ---- Phase C: out[j] = wkv[h,:] . Wv[j,:] ----
    {
        const float4* Wv4 = (const float4*)(Wv + (size_t)tid * KDIM);
        const float4* wv_row = (const float4*)wkv_lds[h];
        float4 oa = {0.f, 0.f, 0.f, 0.f};
        #pragma unroll
        for (int i = 0; i < 16; ++i) {
            float4 w = Wv4[i];
            float4 c = wv_row[i];                        // broadcast
            oa.x = fmaf(c.x, w.x, oa.x);
            oa.y = fmaf(c.y, w.y, oa.y);
            oa.z = fmaf(c.z, w.z, oa.z);
            oa.w = fmaf(c.w, w.w, oa.w);
        }
        out[(size_t)bt * CH + tid] = (oa.x + oa.y) + (oa.z + oa.w);
    }
}

extern "C" void kernel_launch(void* const* d_in, const int* in_sizes, int n_in,
                              void* d_out, int out_size, void* d_ws, size_t ws_size,
                              hipStream_t stream) {
    const float* q_x  = (const float*)d_in[0];
    const float* kv_x = (const float*)d_in[1];
    const float* Wk   = (const float*)d_in[2];
    const float* Wq   = (const float*)d_in[3];
    const float* Wv   = (const float*)d_in[4];
    const float* bias = (const float*)d_in[5];
    const float* Ws   = (const float*)d_in[6];
    const float* bs   = (const float*)d_in[7];
    float* out = (float*)d_out;

    attn_kernel<<<dim3(B * T), dim3(256), 0, stream>>>(
        q_x, kv_x, Wk, Wq, Wv, bias, Ws, bs, out);
}